// Round 15
// baseline (37.903 us; speedup 1.0000x reference)
//
#include <hip/hip_runtime.h>
#include <hip/hip_bf16.h>

// GRU cell: B=16384, IN=256, UNITS=256, K = IN+UNITS = 512.
//   z = sigmoid([h,x]@Wz + bz); r = sigmoid([h,x]@Wr + br)
//   h~ = tanh([r*h, x]@Ws + bs);  h' = (1-z)*h + z*h~
// Round 15: r14 pipeline at 2 blocks/CU. Grid 512, 512 thr, 32 rows/block,
// wave = 32 rows x 32 cols (M=2, N=2). Independent co-resident blocks
// overlap each other's staging/barrier/epilogue bubbles.

#define ROWS 32

typedef float f32x4 __attribute__((ext_vector_type(4)));
typedef __bf16 bf16x8 __attribute__((ext_vector_type(8)));
typedef unsigned short us8 __attribute__((ext_vector_type(8)));
typedef unsigned short us4v __attribute__((ext_vector_type(4)));

static __device__ __forceinline__ unsigned short f2bf(float f) {
    __bf16 h = (__bf16)f;                              // RNE, enables v_cvt_pk
    return __builtin_bit_cast(unsigned short, h);
}
static __device__ __forceinline__ float bf2f(unsigned short u) {
    union { unsigned u; float f; } v; v.u = ((unsigned)u) << 16;
    return v.f;
}

// Pack W[512][256] (fp32 row-major) -> [kt][nt][lane][8] bf16 frags.
__global__ void pack_weights(const float* __restrict__ Wz,
                             const float* __restrict__ Wr,
                             const float* __restrict__ Ws,
                             unsigned short* __restrict__ out) {
    int gid = blockIdx.x * blockDim.x + threadIdx.x;   // 0 .. 49152
    int w    = gid >> 14;
    int rem  = gid & 16383;
    int kt   = rem >> 10;
    int rem2 = rem & 1023;
    int nt   = rem2 >> 6;
    int lane = rem2 & 63;
    int hi = lane >> 4, lo = lane & 15;
    const float* W = (w == 0) ? Wz : (w == 1) ? Wr : Ws;
    const float* src = W + (size_t)(kt * 32 + hi * 8) * 256 + nt * 16 + lo;
    us8 o;
#pragma unroll
    for (int j = 0; j < 8; ++j) o[j] = f2bf(src[(size_t)j * 256]);
    *(us8*)&out[(size_t)w * 131072 + (size_t)(((kt * 16 + nt) * 64 + lane) * 8)] = o;
}

__launch_bounds__(512, 4)
__global__ void gru_main(const float* __restrict__ x,
                         const float* __restrict__ ph,
                         const float* __restrict__ bz,
                         const float* __restrict__ br,
                         const float* __restrict__ bs,
                         const unsigned short* __restrict__ Wp,
                         float* __restrict__ out) {
    __shared__ unsigned short sm[ROWS * 512];          // 32 KiB: [ph | x], swizzled
    __shared__ unsigned short rh[ROWS * 256];          // 16 KiB: r*ph, swizzled

    const int tid  = threadIdx.x;
    const int lane = tid & 63;
    const int wid  = tid >> 6;                         // 0..7: cols [wid*32,+32)
    const int brow = blockIdx.x * ROWS;

    const int l15 = lane & 15;
    const int kg  = (lane >> 4) << 3;                  // k sub-offset 0,8,16,24
    const int c0  = wid * 32 + l15;
    const int c1  = c0 + 16;

    // B-frag bases: frag(kt,nt) at ((kt*16+nt)*64+lane)*8; nt0 = wid*2.
    const unsigned short* pz = Wp          + (size_t)(wid * 128 + lane) * 8;
    const unsigned short* pr = pz + 131072;
    const unsigned short* ps = pz + 262144;
    // prefetch kt=0 z/r frags (fly during staging)
    us8 z0n = *(const us8*)pz;  us8 z1n = *(const us8*)(pz + 512);
    us8 r0n = *(const us8*)pr;  us8 r1n = *(const us8*)(pr + 512);
    const float bz0 = bz[c0], bz1 = bz[c1];
    const float br0 = br[c0], br1 = br[c1];
    const float bs0 = bs[c0], bs1 = bs[c1];

    // ---- stage ph -> k[0,256) as bf16, swizzled ----
#pragma unroll
    for (int it = 0; it < 4; ++it) {
        int i   = tid + it * 512;                      // 2048 float4 total
        int row = i >> 6;
        int c4  = (i & 63) << 2;
        int swr = (row & 7) << 3;
        float4 a = *(const float4*)&ph[(size_t)(brow + row) * 256 + c4];
        us4v u; u.x = f2bf(a.x); u.y = f2bf(a.y); u.z = f2bf(a.z); u.w = f2bf(a.w);
        *(us4v*)&sm[row * 512 + (c4 ^ swr)] = u;
    }
    __syncthreads();                                   // bar1: ph staged

    // ---- x loads to regs: fly under GEMM1a ----
    float4 xr[4];
#pragma unroll
    for (int it = 0; it < 4; ++it) {
        int i   = tid + it * 512;
        int row = i >> 6;
        int c4  = (i & 63) << 2;
        xr[it] = *(const float4*)&x[(size_t)(brow + row) * 256 + c4];
    }

    // ---- GEMM1a: z,r over ph half (kt 0..7), depth-1 B prefetch ----
    f32x4 accz[2][2] = {};
    f32x4 accr[2][2] = {};
#pragma unroll 4
    for (int kt = 0; kt < 8; ++kt) {
        bf16x8 Z0 = __builtin_bit_cast(bf16x8, z0n), Z1 = __builtin_bit_cast(bf16x8, z1n);
        bf16x8 R0 = __builtin_bit_cast(bf16x8, r0n), R1 = __builtin_bit_cast(bf16x8, r1n);
        size_t no = (size_t)(kt + 1) * 8192;
        z0n = *(const us8*)(pz + no); z1n = *(const us8*)(pz + no + 512);
        r0n = *(const us8*)(pr + no); r1n = *(const us8*)(pr + no + 512);
        int ak = kt * 32 + kg;
#pragma unroll
        for (int m = 0; m < 2; ++m) {
            int arow = m * 16 + l15;
            bf16x8 a = __builtin_bit_cast(bf16x8,
                *(const us8*)&sm[arow * 512 + (ak ^ ((arow & 7) << 3))]);
            accz[m][0] = __builtin_amdgcn_mfma_f32_16x16x32_bf16(a, Z0, accz[m][0], 0, 0, 0);
            accz[m][1] = __builtin_amdgcn_mfma_f32_16x16x32_bf16(a, Z1, accz[m][1], 0, 0, 0);
            accr[m][0] = __builtin_amdgcn_mfma_f32_16x16x32_bf16(a, R0, accr[m][0], 0, 0, 0);
            accr[m][1] = __builtin_amdgcn_mfma_f32_16x16x32_bf16(a, R1, accr[m][1], 0, 0, 0);
        }
    }

    // ---- write x (bf16) into k[256,512) ----
#pragma unroll
    for (int it = 0; it < 4; ++it) {
        int i   = tid + it * 512;
        int row = i >> 6;
        int c4  = (i & 63) << 2;
        int swr = (row & 7) << 3;
        us4v v; v.x = f2bf(xr[it].x); v.y = f2bf(xr[it].y);
        v.z = f2bf(xr[it].z); v.w = f2bf(xr[it].w);
        *(us4v*)&sm[row * 512 + ((256 + c4) ^ swr)] = v;
    }
    __syncthreads();                                   // bar2: x staged

    // prefetch Ws kt=8 pair (consumed inside fused GEMM1b)
    us8 s0n = *(const us8*)(ps + (size_t)8 * 8192);
    us8 s1n = *(const us8*)(ps + (size_t)8 * 8192 + 512);

    // ---- GEMM1b FUSED: z,r AND candidate-x over x half (kt 8..15) ----
    f32x4 accs[2][2] = {};
#pragma unroll 4
    for (int kt = 8; kt < 16; ++kt) {
        bf16x8 Z0 = __builtin_bit_cast(bf16x8, z0n), Z1 = __builtin_bit_cast(bf16x8, z1n);
        bf16x8 R0 = __builtin_bit_cast(bf16x8, r0n), R1 = __builtin_bit_cast(bf16x8, r1n);
        bf16x8 S0 = __builtin_bit_cast(bf16x8, s0n), S1 = __builtin_bit_cast(bf16x8, s1n);
        if (kt < 15) {
            size_t no = (size_t)(kt + 1) * 8192;
            z0n = *(const us8*)(pz + no); z1n = *(const us8*)(pz + no + 512);
            r0n = *(const us8*)(pr + no); r1n = *(const us8*)(pr + no + 512);
            s0n = *(const us8*)(ps + no); s1n = *(const us8*)(ps + no + 512);
        }
        int ak = kt * 32 + kg;
#pragma unroll
        for (int m = 0; m < 2; ++m) {
            int arow = m * 16 + l15;
            bf16x8 a = __builtin_bit_cast(bf16x8,
                *(const us8*)&sm[arow * 512 + (ak ^ ((arow & 7) << 3))]);
            accz[m][0] = __builtin_amdgcn_mfma_f32_16x16x32_bf16(a, Z0, accz[m][0], 0, 0, 0);
            accz[m][1] = __builtin_amdgcn_mfma_f32_16x16x32_bf16(a, Z1, accz[m][1], 0, 0, 0);
            accr[m][0] = __builtin_amdgcn_mfma_f32_16x16x32_bf16(a, R0, accr[m][0], 0, 0, 0);
            accr[m][1] = __builtin_amdgcn_mfma_f32_16x16x32_bf16(a, R1, accr[m][1], 0, 0, 0);
            accs[m][0] = __builtin_amdgcn_mfma_f32_16x16x32_bf16(a, S0, accs[m][0], 0, 0, 0);
            accs[m][1] = __builtin_amdgcn_mfma_f32_16x16x32_bf16(a, S1, accs[m][1], 0, 0, 0);
        }
    }

    // prefetch Ws kt=0 pair: latency hides under the sigmoid VALU phase
    s0n = *(const us8*)ps;
    s1n = *(const us8*)(ps + 512);

    // ---- sigmoid; rh -> separate buffer; stash p,z ----
    float pst[2][2][4];
    const int rrow0 = (lane >> 4) * 4;
#pragma unroll
    for (int m = 0; m < 2; ++m)
#pragma unroll
        for (int t = 0; t < 2; ++t)
#pragma unroll
            for (int i = 0; i < 4; ++i) {
                int lrow = m * 16 + rrow0 + i;
                int c  = t ? c1 : c0;
                int cs = c ^ ((lrow & 7) << 3);
                float p = bf2f(sm[lrow * 512 + cs]);
                float z = 1.f / (1.f + __expf(-(accz[m][t][i] + (t ? bz1 : bz0))));
                float r = 1.f / (1.f + __expf(-(accr[m][t][i] + (t ? br1 : br0))));
                accz[m][t][i] = z;
                pst[m][t][i]  = p;
                rh[lrow * 256 + cs] = f2bf(r * p);
            }
    __syncthreads();                                   // bar3: rh ready

    // ---- GEMM2-rh: kt 0..7 from rh ----
#pragma unroll 4
    for (int kt = 0; kt < 8; ++kt) {
        bf16x8 S0 = __builtin_bit_cast(bf16x8, s0n), S1 = __builtin_bit_cast(bf16x8, s1n);
        if (kt < 7) {
            size_t no = (size_t)(kt + 1) * 8192;
            s0n = *(const us8*)(ps + no); s1n = *(const us8*)(ps + no + 512);
        }
        int ak = kt * 32 + kg;
#pragma unroll
        for (int m = 0; m < 2; ++m) {
            int arow = m * 16 + l15;
            bf16x8 a = __builtin_bit_cast(bf16x8,
                *(const us8*)&rh[arow * 256 + (ak ^ ((arow & 7) << 3))]);
            accs[m][0] = __builtin_amdgcn_mfma_f32_16x16x32_bf16(a, S0, accs[m][0], 0, 0, 0);
            accs[m][1] = __builtin_amdgcn_mfma_f32_16x16x32_bf16(a, S1, accs[m][1], 0, 0, 0);
        }
    }

    // ---- epilogue: h' = (1-z)*p + z*tanh(s+bs) ----
#pragma unroll
    for (int m = 0; m < 2; ++m)
#pragma unroll
        for (int t = 0; t < 2; ++t)
#pragma unroll
            for (int i = 0; i < 4; ++i) {
                float s = accs[m][t][i] + (t ? bs1 : bs0);
                float e = __expf(-2.f * fabsf(s));
                float th = (1.f - e) / (1.f + e);
                th = (s < 0.f) ? -th : th;
                float z = accz[m][t][i];
                float p = pst[m][t][i];
                out[(size_t)(brow + m * 16 + rrow0 + i) * 256 + (t ? c1 : c0)]
                    = (1.f - z) * p + z * th;
            }
}

extern "C" void kernel_launch(void* const* d_in, const int* in_sizes, int n_in,
                              void* d_out, int out_size, void* d_ws, size_t ws_size,
                              hipStream_t stream) {
    const float* x  = (const float*)d_in[0];
    const float* ph = (const float*)d_in[1];
    const float* Wz = (const float*)d_in[2];
    const float* bz = (const float*)d_in[3];
    const float* Wr = (const float*)d_in[4];
    const float* br = (const float*)d_in[5];
    const float* Ws = (const float*)d_in[6];
    const float* bs = (const float*)d_in[7];
    unsigned short* Wp = (unsigned short*)d_ws;        // 786432 bytes used

    hipLaunchKernelGGL(pack_weights, dim3(192), dim3(256), 0, stream, Wz, Wr, Ws, Wp);
    hipLaunchKernelGGL(gru_main, dim3(512), dim3(512), 0, stream,
                       x, ph, bz, br, bs, Wp, (float*)d_out);
}